// Round 8
// baseline (214.334 us; speedup 1.0000x reference)
//
#include <hip/hip_runtime.h>

typedef __attribute__((ext_vector_type(8))) short short8;
typedef __attribute__((ext_vector_type(4))) float f32x4;
typedef __attribute__((ext_vector_type(16))) float f32x16;
typedef __attribute__((ext_vector_type(2))) unsigned int u32x2;
typedef __attribute__((ext_vector_type(4))) unsigned int u32x4;
typedef unsigned short u16;
typedef unsigned int u32;

#define MFMA16(a, b, c) __builtin_amdgcn_mfma_f32_16x16x32_bf16((a), (b), (c), 0, 0, 0)
#define MFMA32(a, b, c) __builtin_amdgcn_mfma_f32_32x32x16_bf16((a), (b), (c), 0, 0, 0)

#define BATCH 8
#define NTOK 4096
#define CDIM 256
#define CQK 32
#define LOG2E 1.4426950408889634f

__device__ __forceinline__ u16 f2bf(float f) {
  u32 u = __float_as_uint(f);
  return (u16)((u + 0x7FFFu + ((u >> 16) & 1u)) >> 16);
}
// pack two f32 -> two bf16 (round-half-up) in one u32: bf(a) | bf(b)<<16
__device__ __forceinline__ u32 pack2(float a, float b) {
  const u32 ua = __float_as_uint(a) + 0x8000u;
  const u32 ub = __float_as_uint(b) + 0x8000u;
#if __has_builtin(__builtin_amdgcn_perm)
  return __builtin_amdgcn_perm(ub, ua, 0x07060302u);  // {ua.b2,ua.b3,ub.b2,ub.b3}
#else
  return (ua >> 16) | (ub & 0xFFFF0000u);
#endif
}
__device__ __forceinline__ float fexp2(float x) {
#if __has_builtin(__builtin_amdgcn_exp2f)
  return __builtin_amdgcn_exp2f(x);
#else
  return exp2f(x);
#endif
}

// ---------------------------------------------------------------------------
// Kernel 0: weights -> MFMA B-fragment order + f32 bias.
// ---------------------------------------------------------------------------
__global__ void k_prep(const float* __restrict__ Wq, const float* __restrict__ bq,
                       const float* __restrict__ Wk, const float* __restrict__ bk,
                       const float* __restrict__ Wv, const float* __restrict__ bv,
                       u16* __restrict__ wtf, float* __restrict__ bias) {
  const int f = blockIdx.x;        // 0..159 = ct*8+ks
  const int L = threadIdx.x;       // 0..63
  const int ct = f >> 3, ks = f & 7;
  const int o = ct * 16 + (L & 15);
  const int ch = ks * 32 + (L >> 4) * 8;
  short8 v8;
#pragma unroll
  for (int jj = 0; jj < 8; jj++) {
    const int c = ch + jj;
    float v;
    if (o < 32)       v = Wq[c * CQK + o];
    else if (o < 64)  v = Wk[c * CQK + (o - 32)];
    else              v = Wv[c * CDIM + (o - 64)];
    v8[jj] = (short)f2bf(v);
  }
  *(short8*)(wtf + (size_t)f * 512 + L * 8) = v8;
  if (f == 0) {
    for (int i = L; i < 320; i += 64) {
      if (i < 32)      bias[i] = bq[i];
      else if (i < 64) bias[i] = bk[i - 32];
      else             bias[i] = bv[i - 64];
    }
  }
}

// ---------------------------------------------------------------------------
// Kernel 1: fused cvt+proj. K outputs pre-scaled by log2(e) (exp2 trick).
// q_ws/k_ws row-major [row][32]. V is emitted as ready MFMA32 B-fragments
// with the in-register-P j-permutation baked in:
//   frag(b, t=64-token tile, cg=64-ch group, fid=(jt<<2)|(kh<<1)|ct2):
//   lane l, elem jj holds V[t*64 + 32*jt + 16*kh + 4*(l>>5) + (jj&3)+8*(jj>>2)]
//                          [cg*64 + ct2*32 + (l&31)]
// so k_attn's PV consumes V global->reg with zero LDS staging and the A/B
// k-orders agree by construction (j(k) = (k&3)+8*((k>>2)&1)+4*(k>>3)).
// ---------------------------------------------------------------------------
__global__ __launch_bounds__(256, 2) void k_proj(
    const float* __restrict__ x, const u16* __restrict__ wtf,
    const float* __restrict__ bias,
    u16* __restrict__ q_ws, u16* __restrict__ k_ws, u16* __restrict__ vt_ws) {
  __shared__ u16 x_lds[64 * 264];
  __shared__ u16 vt_t[64 * 76];   // straight [c][n], pad 76 (2-way banks)
  const int m0 = blockIdx.x * 64;
  const int tid = threadIdx.x;
  const int w = tid >> 6, L = tid & 63;
  const int lr = L & 15, q4 = L >> 4;

  // ks=0 weight prefetch (independent of LDS) — flies across the x staging.
  short8 wfA[5], wfB[5];
#pragma unroll
  for (int j = 0; j < 5; j++)
    wfA[j] = *(const short8*)(wtf + ((size_t)((j * 4 + w) * 8 + 0)) * 512 + L * 8);

  // stage + convert x tile via perm-packs
#pragma unroll
  for (int ii = 0; ii < 8; ii++) {
    const int e = (tid + 256 * ii) * 8;
    const int row = e >> 8, col = e & 255;
    const float* src = x + (size_t)(m0 + row) * CDIM + col;
    f32x4 a = *(const f32x4*)src;
    f32x4 b4 = *(const f32x4*)(src + 4);
    u32x4 pk;
    pk[0] = pack2(a[0], a[1]);
    pk[1] = pack2(a[2], a[3]);
    pk[2] = pack2(b4[0], b4[1]);
    pk[3] = pack2(b4[2], b4[3]);
    *(u32x4*)&x_lds[row * 264 + col] = pk;
  }
  __syncthreads();

  f32x4 acc[4][5];
#pragma unroll
  for (int rg = 0; rg < 4; rg++)
#pragma unroll
    for (int j = 0; j < 5; j++) acc[rg][j] = (f32x4){0.f, 0.f, 0.f, 0.f};

#pragma unroll
  for (int ks = 0; ks < 8; ks++) {
    // prefetch next ks-slice into the other buffer (no barriers in this loop)
    if (ks < 7) {
#pragma unroll
      for (int j = 0; j < 5; j++) {
        short8 v = *(const short8*)(wtf +
            ((size_t)((j * 4 + w) * 8 + ks + 1)) * 512 + L * 8);
        if (ks & 1) wfA[j] = v; else wfB[j] = v;
      }
    }
#pragma unroll
    for (int rg = 0; rg < 4; rg++) {
      short8 a = *(const short8*)&x_lds[(rg * 16 + lr) * 264 + ks * 32 + q4 * 8];
#pragma unroll
      for (int j = 0; j < 5; j++)
        acc[rg][j] = MFMA16(a, (ks & 1) ? wfB[j] : wfA[j], acc[rg][j]);
    }
  }

  // q/k epilogue (j=0 -> ct = w; k scaled by log2e). Branch is wave-uniform.
  {
    const float bb = bias[w * 16 + lr];
#pragma unroll
    for (int rg = 0; rg < 4; rg++)
#pragma unroll
      for (int r = 0; r < 4; r++) {
        const int row = m0 + rg * 16 + q4 * 4 + r;
        float v = acc[rg][0][r] + bb;
        if (w < 2) q_ws[(size_t)row * CQK + w * 16 + lr] = f2bf(v);
        else       k_ws[(size_t)row * CQK + (w - 2) * 16 + lr] = f2bf(v * LOG2E);
      }
  }
  // v epilogue: straight transpose via LDS, then B-frag-linear store with
  // the PV j-permutation baked into the gather.
  const int b = m0 >> 12, nt = (m0 & 4095) >> 6;
  const int c_l = w * 16 + lr;
#pragma unroll
  for (int cg = 0; cg < 4; cg++) {
    __syncthreads();
    const int j = cg + 1;
    const float bb = bias[(4 + cg * 4 + w) * 16 + lr];
#pragma unroll
    for (int rg = 0; rg < 4; rg++) {
      u32x2 pk;
      pk[0] = pack2(acc[rg][j][0] + bb, acc[rg][j][1] + bb);
      pk[1] = pack2(acc[rg][j][2] + bb, acc[rg][j][3] + bb);
      *(u32x2*)&vt_t[c_l * 76 + rg * 16 + q4 * 4] = pk;   // straight n
    }
    __syncthreads();
    // fid is wave-uniform per store; lane gathers its 8 permuted tokens.
#pragma unroll
    for (int i = 0; i < 2; i++) {
      const int gch = tid + 256 * i;
      const int fid = gch >> 6;           // (jt<<2)|(kh<<1)|ct2
      const int lane = gch & 63;
      const int jt = fid >> 2, kh = (fid >> 1) & 1, ct2 = fid & 1;
      const int cc = ct2 * 32 + (lane & 31);
      const int n0 = jt * 32 + kh * 16 + (lane >> 5) * 4;
      u32x2 va = *(const u32x2*)&vt_t[cc * 76 + n0];       // tokens n0..n0+3
      u32x2 vb2 = *(const u32x2*)&vt_t[cc * 76 + n0 + 8];  // tokens n0+8..+11
      u32x4 vv = {va[0], va[1], vb2[0], vb2[1]};
      *(short8*)(vt_ws +
          ((((size_t)(b * 64 + nt) * 4 + cg) * 8 + fid) * 512) + lane * 8) =
          __builtin_bit_cast(short8, vv);
    }
  }
}

// ---------------------------------------------------------------------------
// Kernel 2: flash attention with fully in-register P — ZERO barriers, zero
// hot-loop LDS. S^T via MFMA32(A=Q, B=K^T) leaves S for i=lane&31 in-lane,
// which is exactly PV's A-operand row. exp+pack2 in-register; V B-frags
// (pre-permuted by k_proj) loaded global->reg, so waves are fully
// independent: wave = (b, 64-i window, 64-ch block). Row sums complete
// per-lane (+ one shfl_xor(32)); no cross-wave softmax merge.
// Cost: S recomputed per ch-wave (4x) — 24 MFMA32/wave-iter, floor ~41 us —
// paid for by removing the barrier-locked chain that pinned r5-r7 at 90 us.
// ---------------------------------------------------------------------------
__global__ __launch_bounds__(256, 2) void k_attn(
    const float* __restrict__ x, const u16* __restrict__ q_ws,
    const u16* __restrict__ k_ws, const u16* __restrict__ vt_ws,
    const float* __restrict__ gamma, float* __restrict__ out) {
  __shared__ float lp4[4][64];          // per-wave 1/rowsum slices (1 KB)

  const int bid = blockIdx.x;
  const int b = bid & 7;                // same-b blocks land on one XCD
  const int i0 = (bid >> 3) * 64;
  const int tid = threadIdx.x;
  const int w = tid >> 6, L = tid & 63; // wave w = 64-ch block
  const int L31 = L & 31, Lhi = L >> 5;

  // K^T B-frags (persistent): lane holds K[i0+ih*32+L31][h*16 + Lhi*8 ..+8]
  const u16* kb = k_ws + ((size_t)(b * NTOK + i0 + L31)) * CQK + Lhi * 8;
  // Q A-frags: lane holds Q[j0+jt*32+L31][h*16 + Lhi*8 ..+8]
  const u16* qb = q_ws + ((size_t)(b * NTOK) + L31) * CQK + Lhi * 8;
  // V B-frags: base for (b, wave w); +t*16384 +fid*512 +lane*8 (u16 units)
  const u16* vb = vt_ws + ((size_t)b << 20) + w * 4096 + (size_t)L * 8;

  f32x16 z16;
#pragma unroll
  for (int e = 0; e < 16; e++) z16[e] = 0.f;
  f32x16 o00 = z16, o01 = z16, o10 = z16, o11 = z16;
  float ls0 = 0.f, ls1 = 0.f;

  // prologue: V(0), K (persistent), Q(0)
  short8 vV0 = *(const short8*)(vb + 0 * 512);
  short8 vV1 = *(const short8*)(vb + 1 * 512);
  short8 vV2 = *(const short8*)(vb + 2 * 512);
  short8 vV3 = *(const short8*)(vb + 3 * 512);
  short8 vV4 = *(const short8*)(vb + 4 * 512);
  short8 vV5 = *(const short8*)(vb + 5 * 512);
  short8 vV6 = *(const short8*)(vb + 6 * 512);
  short8 vV7 = *(const short8*)(vb + 7 * 512);
  const short8 kf00 = *(const short8*)(kb);
  const short8 kf01 = *(const short8*)(kb + 16);
  const short8 kf10 = *(const short8*)(kb + 32 * CQK);
  const short8 kf11 = *(const short8*)(kb + 32 * CQK + 16);
  short8 q00 = *(const short8*)(qb);
  short8 q01 = *(const short8*)(qb + 16);
  short8 q10 = *(const short8*)(qb + 32 * CQK);
  short8 q11 = *(const short8*)(qb + 32 * CQK + 16);

// exp + pack + 4 PV MFMAs for one S unit (16 f32 -> two A-frags)
#define EPPV(SV, V0, V1, V2, V3, OA, OB, LS)                                   \
  do {                                                                         \
    float e0 = fexp2((SV)[0]), e1 = fexp2((SV)[1]);                            \
    float e2 = fexp2((SV)[2]), e3 = fexp2((SV)[3]);                            \
    float e4 = fexp2((SV)[4]), e5 = fexp2((SV)[5]);                            \
    float e6 = fexp2((SV)[6]), e7 = fexp2((SV)[7]);                            \
    float e8 = fexp2((SV)[8]), e9 = fexp2((SV)[9]);                            \
    float e10 = fexp2((SV)[10]), e11 = fexp2((SV)[11]);                        \
    float e12 = fexp2((SV)[12]), e13 = fexp2((SV)[13]);                        \
    float e14 = fexp2((SV)[14]), e15 = fexp2((SV)[15]);                        \
    LS += ((((e0 + e1) + (e2 + e3)) + ((e4 + e5) + (e6 + e7))) +               \
           (((e8 + e9) + (e10 + e11)) + ((e12 + e13) + (e14 + e15))));         \
    u32x4 pA = {pack2(e0, e1), pack2(e2, e3), pack2(e4, e5), pack2(e6, e7)};   \
    u32x4 pB = {pack2(e8, e9), pack2(e10, e11), pack2(e12, e13),               \
                pack2(e14, e15)};                                              \
    const short8 a0 = __builtin_bit_cast(short8, pA);                          \
    const short8 a1 = __builtin_bit_cast(short8, pB);                          \
    OA = MFMA32(a0, V0, OA);                                                   \
    OB = MFMA32(a0, V1, OB);                                                   \
    OA = MFMA32(a1, V2, OA);                                                   \
    OB = MFMA32(a1, V3, OB);                                                   \
  } while (0)

#define UNIT(QA, QB, KA, KB, V0, V1, V2, V3, OA, OB, LS)                       \
  do {                                                                         \
    f32x16 sv_ = MFMA32(QA, KA, z16);                                          \
    sv_ = MFMA32(QB, KB, sv_);                                                 \
    EPPV(sv_, V0, V1, V2, V3, OA, OB, LS);                                     \
  } while (0)

  for (int t = 0; t < 64; ++t) {
    const size_t vn = (size_t)(t + 1) * 16384;        // next V tile (u16)
    UNIT(q00, q01, kf00, kf01, vV0, vV1, vV2, vV3, o00, o01, ls0);  // ih0 jt0
    UNIT(q10, q11, kf00, kf01, vV4, vV5, vV6, vV7, o00, o01, ls0);  // ih0 jt1
    UNIT(q00, q01, kf10, kf11, vV0, vV1, vV2, vV3, o10, o11, ls1);  // ih1 jt0
    // jt0 V-frags dead -> reload for t+1 (consumed after a full unit of slack;
    // t=63 reads land in wtf region: allocated, unused garbage)
    vV0 = *(const short8*)(vb + vn + 0 * 512);
    vV1 = *(const short8*)(vb + vn + 1 * 512);
    vV2 = *(const short8*)(vb + vn + 2 * 512);
    vV3 = *(const short8*)(vb + vn + 3 * 512);
    // ih1 jt1, split: S first, Q(t+1) reloads hide under the MFMA latency
    f32x16 svz = MFMA32(q10, kf10, z16);
    svz = MFMA32(q11, kf11, svz);
    {
      const size_t qo = (size_t)(t + 1) * 64 * CQK;   // t=63 -> lands in k_ws
      q00 = *(const short8*)(qb + qo);
      q01 = *(const short8*)(qb + qo + 16);
      q10 = *(const short8*)(qb + qo + 32 * CQK);
      q11 = *(const short8*)(qb + qo + 32 * CQK + 16);
    }
    EPPV(svz, vV4, vV5, vV6, vV7, o10, o11, ls1);
    vV4 = *(const short8*)(vb + vn + 4 * 512);
    vV5 = *(const short8*)(vb + vn + 5 * 512);
    vV6 = *(const short8*)(vb + vn + 6 * 512);
    vV7 = *(const short8*)(vb + vn + 7 * 512);
  }
#undef UNIT
#undef EPPV

  // row sums: lane holds half the j's for i = L31 (per ih); merge hi-halves.
  ls0 += __shfl_xor(ls0, 32);
  ls1 += __shfl_xor(ls1, 32);
  if (L < 32) {
    lp4[w][L] = 1.0f / ls0;
    lp4[w][32 + L] = 1.0f / ls1;
  }
  asm volatile("s_waitcnt lgkmcnt(0)" ::: "memory");  // intra-wave LDS RAW

  float linv[2][16];
#pragma unroll
  for (int ih = 0; ih < 2; ih++)
#pragma unroll
    for (int rg = 0; rg < 16; rg++)
      linv[ih][rg] = lp4[w][ih * 32 + (rg & 3) + 8 * (rg >> 2) + 4 * Lhi];

  const float g = gamma[0];
#define STO(OV, IH, CT2)                                                       \
  _Pragma("unroll")                                                            \
  for (int rg = 0; rg < 16; rg++) {                                            \
    const int i = i0 + (IH) * 32 + (rg & 3) + 8 * (rg >> 2) + 4 * Lhi;         \
    const int c = w * 64 + (CT2) * 32 + L31;                                   \
    const size_t idx = ((size_t)(b * NTOK + i)) * CDIM + c;                    \
    out[idx] = g * (OV[rg] * linv[IH][rg]) + x[idx];                           \
  }
  STO(o00, 0, 0)
  STO(o01, 0, 1)
  STO(o10, 1, 0)
  STO(o11, 1, 1)
#undef STO
}

// ---------------------------------------------------------------------------
extern "C" void kernel_launch(void* const* d_in, const int* in_sizes, int n_in,
                              void* d_out, int out_size, void* d_ws, size_t ws_size,
                              hipStream_t stream) {
  const float* x  = (const float*)d_in[0];
  const float* Wq = (const float*)d_in[1];
  const float* bq = (const float*)d_in[2];
  const float* Wk = (const float*)d_in[3];
  const float* bk = (const float*)d_in[4];
  const float* Wv = (const float*)d_in[5];
  const float* bv = (const float*)d_in[6];
  const float* gamma = (const float*)d_in[7];
  float* out = (float*)d_out;

  char* ws = (char*)d_ws;
  u16* q_ws  = (u16*)(ws);
  u16* k_ws  = (u16*)(ws + (2u << 20));
  u16* vt_ws = (u16*)(ws + (4u << 20));
  u16* wtf   = (u16*)(ws + (20u << 20));
  float* bias = (float*)(ws + (20u << 20) + (256u << 10));

  k_prep<<<160, 64, 0, stream>>>(Wq, bq, Wk, bk, Wv, bv, wtf, bias);
  k_proj<<<512, 256, 0, stream>>>(x, wtf, bias, q_ws, k_ws, vt_ws);
  k_attn<<<512, 256, 0, stream>>>(x, q_ws, k_ws, vt_ws, gamma, out);
}

// Round 9
// 205.614 us; speedup vs baseline: 1.0424x; 1.0424x over previous
//
#include <hip/hip_runtime.h>

typedef __attribute__((ext_vector_type(8))) short short8;
typedef __attribute__((ext_vector_type(4))) float f32x4;
typedef __attribute__((ext_vector_type(16))) float f32x16;
typedef __attribute__((ext_vector_type(2))) unsigned int u32x2;
typedef __attribute__((ext_vector_type(4))) unsigned int u32x4;
typedef unsigned short u16;
typedef unsigned int u32;

#define MFMA16(a, b, c) __builtin_amdgcn_mfma_f32_16x16x32_bf16((a), (b), (c), 0, 0, 0)
#define MFMA32(a, b, c) __builtin_amdgcn_mfma_f32_32x32x16_bf16((a), (b), (c), 0, 0, 0)

#define BATCH 8
#define NTOK 4096
#define CDIM 256
#define CQK 32
#define LOG2E 1.4426950408889634f

__device__ __forceinline__ u16 f2bf(float f) {
  u32 u = __float_as_uint(f);
  return (u16)((u + 0x7FFFu + ((u >> 16) & 1u)) >> 16);
}
// pack two f32 -> two bf16 (round-half-up) in one u32: bf(a) | bf(b)<<16
__device__ __forceinline__ u32 pack2(float a, float b) {
  const u32 ua = __float_as_uint(a) + 0x8000u;
  const u32 ub = __float_as_uint(b) + 0x8000u;
#if __has_builtin(__builtin_amdgcn_perm)
  return __builtin_amdgcn_perm(ub, ua, 0x07060302u);  // {ua.b2,ua.b3,ub.b2,ub.b3}
#else
  return (ua >> 16) | (ub & 0xFFFF0000u);
#endif
}
__device__ __forceinline__ float fexp2(float x) {
#if __has_builtin(__builtin_amdgcn_exp2f)
  return __builtin_amdgcn_exp2f(x);
#else
  return exp2f(x);
#endif
}

// ---------------------------------------------------------------------------
// Kernel 0: weights -> MFMA B-fragment order + f32 bias.
// ---------------------------------------------------------------------------
__global__ void k_prep(const float* __restrict__ Wq, const float* __restrict__ bq,
                       const float* __restrict__ Wk, const float* __restrict__ bk,
                       const float* __restrict__ Wv, const float* __restrict__ bv,
                       u16* __restrict__ wtf, float* __restrict__ bias) {
  const int f = blockIdx.x;        // 0..159 = ct*8+ks
  const int L = threadIdx.x;       // 0..63
  const int ct = f >> 3, ks = f & 7;
  const int o = ct * 16 + (L & 15);
  const int ch = ks * 32 + (L >> 4) * 8;
  short8 v8;
#pragma unroll
  for (int jj = 0; jj < 8; jj++) {
    const int c = ch + jj;
    float v;
    if (o < 32)       v = Wq[c * CQK + o];
    else if (o < 64)  v = Wk[c * CQK + (o - 32)];
    else              v = Wv[c * CDIM + (o - 64)];
    v8[jj] = (short)f2bf(v);
  }
  *(short8*)(wtf + (size_t)f * 512 + L * 8) = v8;
  if (f == 0) {
    for (int i = L; i < 320; i += 64) {
      if (i < 32)      bias[i] = bq[i];
      else if (i < 64) bias[i] = bk[i - 32];
      else             bias[i] = bv[i - 64];
    }
  }
}

// ---------------------------------------------------------------------------
// Kernel 1: fused cvt+proj. K outputs pre-scaled by log2(e) (exp2 trick).
// q_ws/k_ws row-major [row][32]. V is emitted as ready MFMA32 B-fragments
// with the in-register-P j-permutation baked in:
//   frag(b, t=64-token tile, cg=64-ch group, fid=(jt<<2)|(kh<<1)|ct2):
//   lane l, elem jj holds V[t*64 + 32*jt + 16*kh + 4*(l>>5) + (jj&3)+8*(jj>>2)]
//                          [cg*64 + ct2*32 + (l&31)]
// so k_attn's PV consumes V global->reg with zero LDS staging and the A/B
// k-orders agree by construction (j(k) = (k&3)+8*((k>>2)&1)+4*(k>>3)).
// ---------------------------------------------------------------------------
__global__ __launch_bounds__(256, 2) void k_proj(
    const float* __restrict__ x, const u16* __restrict__ wtf,
    const float* __restrict__ bias,
    u16* __restrict__ q_ws, u16* __restrict__ k_ws, u16* __restrict__ vt_ws) {
  __shared__ u16 x_lds[64 * 264];
  __shared__ u16 vt_t[64 * 76];   // straight [c][n], pad 76 (2-way banks)
  const int m0 = blockIdx.x * 64;
  const int tid = threadIdx.x;
  const int w = tid >> 6, L = tid & 63;
  const int lr = L & 15, q4 = L >> 4;

  // ks=0 weight prefetch (independent of LDS) — flies across the x staging.
  short8 wfA[5], wfB[5];
#pragma unroll
  for (int j = 0; j < 5; j++)
    wfA[j] = *(const short8*)(wtf + ((size_t)((j * 4 + w) * 8 + 0)) * 512 + L * 8);

  // stage + convert x tile via perm-packs
#pragma unroll
  for (int ii = 0; ii < 8; ii++) {
    const int e = (tid + 256 * ii) * 8;
    const int row = e >> 8, col = e & 255;
    const float* src = x + (size_t)(m0 + row) * CDIM + col;
    f32x4 a = *(const f32x4*)src;
    f32x4 b4 = *(const f32x4*)(src + 4);
    u32x4 pk;
    pk[0] = pack2(a[0], a[1]);
    pk[1] = pack2(a[2], a[3]);
    pk[2] = pack2(b4[0], b4[1]);
    pk[3] = pack2(b4[2], b4[3]);
    *(u32x4*)&x_lds[row * 264 + col] = pk;
  }
  __syncthreads();

  f32x4 acc[4][5];
#pragma unroll
  for (int rg = 0; rg < 4; rg++)
#pragma unroll
    for (int j = 0; j < 5; j++) acc[rg][j] = (f32x4){0.f, 0.f, 0.f, 0.f};

#pragma unroll
  for (int ks = 0; ks < 8; ks++) {
    // prefetch next ks-slice into the other buffer (no barriers in this loop)
    if (ks < 7) {
#pragma unroll
      for (int j = 0; j < 5; j++) {
        short8 v = *(const short8*)(wtf +
            ((size_t)((j * 4 + w) * 8 + ks + 1)) * 512 + L * 8);
        if (ks & 1) wfA[j] = v; else wfB[j] = v;
      }
    }
#pragma unroll
    for (int rg = 0; rg < 4; rg++) {
      short8 a = *(const short8*)&x_lds[(rg * 16 + lr) * 264 + ks * 32 + q4 * 8];
#pragma unroll
      for (int j = 0; j < 5; j++)
        acc[rg][j] = MFMA16(a, (ks & 1) ? wfB[j] : wfA[j], acc[rg][j]);
    }
  }

  // q/k epilogue (j=0 -> ct = w; k scaled by log2e). Branch is wave-uniform.
  {
    const float bb = bias[w * 16 + lr];
#pragma unroll
    for (int rg = 0; rg < 4; rg++)
#pragma unroll
      for (int r = 0; r < 4; r++) {
        const int row = m0 + rg * 16 + q4 * 4 + r;
        float v = acc[rg][0][r] + bb;
        if (w < 2) q_ws[(size_t)row * CQK + w * 16 + lr] = f2bf(v);
        else       k_ws[(size_t)row * CQK + (w - 2) * 16 + lr] = f2bf(v * LOG2E);
      }
  }
  // v epilogue: straight transpose via LDS, then B-frag-linear store with
  // the PV j-permutation baked into the gather.
  const int b = m0 >> 12, nt = (m0 & 4095) >> 6;
  const int c_l = w * 16 + lr;
#pragma unroll
  for (int cg = 0; cg < 4; cg++) {
    __syncthreads();
    const int j = cg + 1;
    const float bb = bias[(4 + cg * 4 + w) * 16 + lr];
#pragma unroll
    for (int rg = 0; rg < 4; rg++) {
      u32x2 pk;
      pk[0] = pack2(acc[rg][j][0] + bb, acc[rg][j][1] + bb);
      pk[1] = pack2(acc[rg][j][2] + bb, acc[rg][j][3] + bb);
      *(u32x2*)&vt_t[c_l * 76 + rg * 16 + q4 * 4] = pk;   // straight n
    }
    __syncthreads();
    // fid is wave-uniform per store; lane gathers its 8 permuted tokens.
#pragma unroll
    for (int i = 0; i < 2; i++) {
      const int gch = tid + 256 * i;
      const int fid = gch >> 6;           // (jt<<2)|(kh<<1)|ct2
      const int lane = gch & 63;
      const int jt = fid >> 2, kh = (fid >> 1) & 1, ct2 = fid & 1;
      const int cc = ct2 * 32 + (lane & 31);
      const int n0 = jt * 32 + kh * 16 + (lane >> 5) * 4;
      u32x2 va = *(const u32x2*)&vt_t[cc * 76 + n0];       // tokens n0..n0+3
      u32x2 vb2 = *(const u32x2*)&vt_t[cc * 76 + n0 + 8];  // tokens n0+8..+11
      u32x4 vv = {va[0], va[1], vb2[0], vb2[1]};
      *(short8*)(vt_ws +
          ((((size_t)(b * 64 + nt) * 4 + cg) * 8 + fid) * 512) + lane * 8) =
          __builtin_bit_cast(short8, vv);
    }
  }
}

// ---------------------------------------------------------------------------
// Kernel 2: flash attention, in-register P, wave = (b, 32 i-rows, 128 ch).
// vs r8 (64i x 64ch): softmax duplication drops 4x -> 2x (exp/pack VALU
// halves — r8 was VALU-bound at 60% busy), S-MFMA halves; PV work identical.
// Still ZERO barriers / zero hot-loop LDS: S^T = MFMA32(Q, K^T) leaves S
// for i=lane&31 in-lane = PV's A-row; exp+pack in-register; V B-frags
// (pre-permuted by k_proj) stream global->reg one t-tile ahead.
// Per wave-iter: 4 S-MFMA32 + 16 PV-MFMA32, 32 exps/lane.
// ---------------------------------------------------------------------------
__global__ __launch_bounds__(256, 2) void k_attn(
    const float* __restrict__ x, const u16* __restrict__ q_ws,
    const u16* __restrict__ k_ws, const u16* __restrict__ vt_ws,
    const float* __restrict__ gamma, float* __restrict__ out) {
  __shared__ float lp4[4][32];          // per-wave 1/rowsum (wave-private)

  const int bid = blockIdx.x;
  const int b = bid & 7;                // same-b blocks land on one XCD
  const int tid = threadIdx.x;
  const int w = tid >> 6, L = tid & 63;
  const int L31 = L & 31, Lhi = L >> 5;
  const int i0 = (bid >> 3) * 64 + (w >> 1) * 32;  // 32-i window
  const int chh = w & 1;                           // 128-ch half

  // K^T B-frags (persistent): lane holds K[i0+L31][Lhi*8 ..+8 (+16)]
  const u16* kb = k_ws + ((size_t)(b * NTOK + i0 + L31)) * CQK + Lhi * 8;
  const short8 kf0 = *(const short8*)(kb);
  const short8 kf1 = *(const short8*)(kb + 16);
  // Q A-frags: lane holds Q[j0+L31][Lhi*8 ..+8 (+16)]
  const u16* qb = q_ws + ((size_t)(b * NTOK) + L31) * CQK + Lhi * 8;
  // V frag base for this wave's 128-ch half (cg = chh*2 + cb2):
  //   + t*16384 + cb2*4096 + fid*512, fid = (jt<<2)|(kh<<1)|ct2
  const u16* vb = vt_ws + ((size_t)b << 20) + (size_t)(chh * 2) * 4096 +
                  (size_t)L * 8;

  f32x16 z16;
#pragma unroll
  for (int e = 0; e < 16; e++) z16[e] = 0.f;
  f32x16 o00 = z16, o01 = z16, o10 = z16, o11 = z16;  // [cb2][ct2]
  float ls = 0.f;

  // prologue: V(0) 16 frags; Q(0)
  // jt0 set u*: u0..u3 = cb2 0 (kh0ct0,kh0ct1,kh1ct0,kh1ct1), u4..u7 = cb2 1
  short8 u0 = *(const short8*)(vb + 0);
  short8 u1 = *(const short8*)(vb + 512);
  short8 u2 = *(const short8*)(vb + 1024);
  short8 u3 = *(const short8*)(vb + 1536);
  short8 u4 = *(const short8*)(vb + 4096);
  short8 u5 = *(const short8*)(vb + 4096 + 512);
  short8 u6 = *(const short8*)(vb + 4096 + 1024);
  short8 u7 = *(const short8*)(vb + 4096 + 1536);
  // jt1 set v*: fid 4..7 -> +2048
  short8 v0 = *(const short8*)(vb + 2048);
  short8 v1 = *(const short8*)(vb + 2048 + 512);
  short8 v2 = *(const short8*)(vb + 2048 + 1024);
  short8 v3 = *(const short8*)(vb + 2048 + 1536);
  short8 v4 = *(const short8*)(vb + 4096 + 2048);
  short8 v5 = *(const short8*)(vb + 4096 + 2048 + 512);
  short8 v6 = *(const short8*)(vb + 4096 + 2048 + 1024);
  short8 v7 = *(const short8*)(vb + 4096 + 2048 + 1536);
  short8 q00 = *(const short8*)(qb);
  short8 q01 = *(const short8*)(qb + 16);
  short8 q10 = *(const short8*)(qb + 32 * CQK);
  short8 q11 = *(const short8*)(qb + 32 * CQK + 16);

// exp + pack + 8 PV MFMAs for one 32-j unit across 128 ch.
// a0 (e0..e7) pairs with kh0 frags (W0,W1,W4,W5); a1 with kh1 (W2,W3,W6,W7).
#define EPPV(SV, W0, W1, W2, W3, W4, W5, W6, W7)                               \
  do {                                                                         \
    float e0 = fexp2((SV)[0]), e1 = fexp2((SV)[1]);                            \
    float e2 = fexp2((SV)[2]), e3 = fexp2((SV)[3]);                            \
    float e4 = fexp2((SV)[4]), e5 = fexp2((SV)[5]);                            \
    float e6 = fexp2((SV)[6]), e7 = fexp2((SV)[7]);                            \
    float e8 = fexp2((SV)[8]), e9 = fexp2((SV)[9]);                            \
    float e10 = fexp2((SV)[10]), e11 = fexp2((SV)[11]);                        \
    float e12 = fexp2((SV)[12]), e13 = fexp2((SV)[13]);                        \
    float e14 = fexp2((SV)[14]), e15 = fexp2((SV)[15]);                        \
    ls += ((((e0 + e1) + (e2 + e3)) + ((e4 + e5) + (e6 + e7))) +               \
           (((e8 + e9) + (e10 + e11)) + ((e12 + e13) + (e14 + e15))));         \
    u32x4 pA = {pack2(e0, e1), pack2(e2, e3), pack2(e4, e5), pack2(e6, e7)};   \
    u32x4 pB = {pack2(e8, e9), pack2(e10, e11), pack2(e12, e13),               \
                pack2(e14, e15)};                                              \
    const short8 a0 = __builtin_bit_cast(short8, pA);                          \
    const short8 a1 = __builtin_bit_cast(short8, pB);                          \
    o00 = MFMA32(a0, W0, o00);                                                 \
    o01 = MFMA32(a0, W1, o01);                                                 \
    o10 = MFMA32(a0, W4, o10);                                                 \
    o11 = MFMA32(a0, W5, o11);                                                 \
    o00 = MFMA32(a1, W2, o00);                                                 \
    o01 = MFMA32(a1, W3, o01);                                                 \
    o10 = MFMA32(a1, W6, o10);                                                 \
    o11 = MFMA32(a1, W7, o11);                                                 \
  } while (0)

  for (int t = 0; t < 64; ++t) {
    const u16* vn = vb + (size_t)(t + 1) * 16384;     // next V tile
    // S jt0 (j = t*64 .. +31): lane holds S[j rows][i=L31]
    f32x16 sv0 = MFMA32(q00, kf0, z16);
    sv0 = MFMA32(q01, kf1, sv0);
    EPPV(sv0, u0, u1, u2, u3, u4, u5, u6, u7);
    // jt0 V-frags dead -> reload for t+1 (t=63 overrun lands in wtf: unused)
    u0 = *(const short8*)(vn + 0);
    u1 = *(const short8*)(vn + 512);
    u2 = *(const short8*)(vn + 1024);
    u3 = *(const short8*)(vn + 1536);
    u4 = *(const short8*)(vn + 4096);
    u5 = *(const short8*)(vn + 4096 + 512);
    u6 = *(const short8*)(vn + 4096 + 1024);
    u7 = *(const short8*)(vn + 4096 + 1536);
    // S jt1; then Q regs dead -> reload Q(t+1) under the MFMA latency
    f32x16 sv1 = MFMA32(q10, kf0, z16);
    sv1 = MFMA32(q11, kf1, sv1);
    {
      const size_t qo = (size_t)(t + 1) * 64 * CQK;   // t=63 -> lands in k_ws
      q00 = *(const short8*)(qb + qo);
      q01 = *(const short8*)(qb + qo + 16);
      q10 = *(const short8*)(qb + qo + 32 * CQK);
      q11 = *(const short8*)(qb + qo + 32 * CQK + 16);
    }
    EPPV(sv1, v0, v1, v2, v3, v4, v5, v6, v7);
    v0 = *(const short8*)(vn + 2048);
    v1 = *(const short8*)(vn + 2048 + 512);
    v2 = *(const short8*)(vn + 2048 + 1024);
    v3 = *(const short8*)(vn + 2048 + 1536);
    v4 = *(const short8*)(vn + 4096 + 2048);
    v5 = *(const short8*)(vn + 4096 + 2048 + 512);
    v6 = *(const short8*)(vn + 4096 + 2048 + 1024);
    v7 = *(const short8*)(vn + 4096 + 2048 + 1536);
  }
#undef EPPV

  // rowsum for i = L31: merge the Lhi j-halves, then wave-private LDS
  // redistribution (lane is c-indexed in the output).
  ls += __shfl_xor(ls, 32);
  if (L < 32) lp4[w][L] = 1.0f / ls;
  asm volatile("s_waitcnt lgkmcnt(0)" ::: "memory");  // intra-wave LDS RAW

  float linv[16];
#pragma unroll
  for (int rg = 0; rg < 16; rg++)
    linv[rg] = lp4[w][(rg & 3) + 8 * (rg >> 2) + 4 * Lhi];

  const float g = gamma[0];
#define STO(OV, CB2, CT2)                                                      \
  _Pragma("unroll")                                                            \
  for (int rg = 0; rg < 16; rg++) {                                            \
    const int i = i0 + (rg & 3) + 8 * (rg >> 2) + 4 * Lhi;                     \
    const int c = (chh * 2 + (CB2)) * 64 + (CT2) * 32 + L31;                   \
    const size_t idx = ((size_t)(b * NTOK + i)) * CDIM + c;                    \
    out[idx] = g * (OV[rg] * linv[rg]) + x[idx];                               \
  }
  STO(o00, 0, 0)
  STO(o01, 0, 1)
  STO(o10, 1, 0)
  STO(o11, 1, 1)
#undef STO
}

// ---------------------------------------------------------------------------
extern "C" void kernel_launch(void* const* d_in, const int* in_sizes, int n_in,
                              void* d_out, int out_size, void* d_ws, size_t ws_size,
                              hipStream_t stream) {
  const float* x  = (const float*)d_in[0];
  const float* Wq = (const float*)d_in[1];
  const float* bq = (const float*)d_in[2];
  const float* Wk = (const float*)d_in[3];
  const float* bk = (const float*)d_in[4];
  const float* Wv = (const float*)d_in[5];
  const float* bv = (const float*)d_in[6];
  const float* gamma = (const float*)d_in[7];
  float* out = (float*)d_out;

  char* ws = (char*)d_ws;
  u16* q_ws  = (u16*)(ws);
  u16* k_ws  = (u16*)(ws + (2u << 20));
  u16* vt_ws = (u16*)(ws + (4u << 20));
  u16* wtf   = (u16*)(ws + (20u << 20));
  float* bias = (float*)(ws + (20u << 20) + (256u << 10));

  k_prep<<<160, 64, 0, stream>>>(Wq, bq, Wk, bk, Wv, bv, wtf, bias);
  k_proj<<<512, 256, 0, stream>>>(x, wtf, bias, q_ws, k_ws, vt_ws);
  k_attn<<<512, 256, 0, stream>>>(x, q_ws, k_ws, vt_ws, gamma, out);
}